// Round 1
// baseline (428.831 us; speedup 1.0000x reference)
//
#include <hip/hip_runtime.h>

typedef __attribute__((ext_vector_type(8))) short short8;
typedef __attribute__((ext_vector_type(4))) float f32x4;
typedef unsigned short u16;
typedef unsigned int u32;

#define DEVFN static __device__ __forceinline__

DEVFN u16 f2b(float f) {
  u32 u = __builtin_bit_cast(u32, f);
  u32 r = u + 0x7fffu + ((u >> 16) & 1u);
  return (u16)(r >> 16);
}

DEVFN short8 ldfrag(const void* p) {
  return __builtin_bit_cast(short8, *(const uint4*)p);
}

#define MFMA16(a, b, c) __builtin_amdgcn_mfma_f32_16x16x32_bf16((a), (b), (c), 0, 0, 0)

DEVFN float gelu_exact(float v) {
  return 0.5f * v * (1.0f + erff(v * 0.70710678118654752f));
}

// ---------------- f32 -> bf16 convert ----------------
__global__ void k_f2b(const float* __restrict__ in, u16* __restrict__ out, int n4) {
  int i = blockIdx.x * 256 + threadIdx.x;
  if (i >= n4) return;
  float4 v = ((const float4*)in)[i];
  ushort4 o = { f2b(v.x), f2b(v.y), f2b(v.z), f2b(v.w) };
  ((ushort4*)out)[i] = o;
}

// ---------------- LayerNorm (256 cols), f32 in -> bf16 out ----------------
__global__ __launch_bounds__(256) void k_ln(const float* __restrict__ x,
                                            const float* __restrict__ g,
                                            const float* __restrict__ b,
                                            u16* __restrict__ out) {
  int row = blockIdx.x * 4 + (threadIdx.x >> 6);
  int l = threadIdx.x & 63;
  const float4 v = *(const float4*)(x + (size_t)row * 256 + l * 4);
  float s = v.x + v.y + v.z + v.w;
#pragma unroll
  for (int m = 1; m < 64; m <<= 1) s += __shfl_xor(s, m);
  float mu = s * (1.0f / 256.0f);
  float dx = v.x - mu, dy = v.y - mu, dz = v.z - mu, dw = v.w - mu;
  float q = dx * dx + dy * dy + dz * dz + dw * dw;
#pragma unroll
  for (int m = 1; m < 64; m <<= 1) q += __shfl_xor(q, m);
  float r = rsqrtf(q * (1.0f / 256.0f) + 1e-5f);
  float4 gv = *(const float4*)(g + l * 4);
  float4 bv = *(const float4*)(b + l * 4);
  ushort4 o = { f2b(dx * r * gv.x + bv.x), f2b(dy * r * gv.y + bv.y),
                f2b(dz * r * gv.z + bv.z), f2b(dw * r * gv.w + bv.w) };
  *(ushort4*)(out + (size_t)row * 256 + l * 4) = o;
}

// ---------------- GEMM: C[M,N] = A[M,K] * B[N,K]^T, bf16 inputs ----------------
// EPI 0: bf16 store            EPI 1: bf16 transposed store (out[col*M+row])
// EPI 2: f32 store + bias + f32 residual     EPI 3: bf16 store + bias + GELU
template <int EPI>
__global__ __launch_bounds__(256, 2) void k_gemm(const u16* __restrict__ A,
                                                 const u16* __restrict__ B,
                                                 void* __restrict__ out,
                                                 const float* __restrict__ bias,
                                                 const float* __restrict__ resid,
                                                 int M, int N, int K) {
  __shared__ __attribute__((aligned(16))) u16 As[128 * 32];
  __shared__ __attribute__((aligned(16))) u16 Bs[128 * 32];
  const int t = threadIdx.x;
  const int w = t >> 6, l = t & 63, g = l >> 4, c = l & 15;
  const int wr = w >> 1, wc = w & 1;
  const int bm = blockIdx.y, bn = blockIdx.x;

  f32x4 acc[4][4] = {};
  const int nk = K >> 5;

  const int srow = t >> 2;      // 0..63 (second issue adds 64)
  const int sj = t & 3;         // 16B slot within 64B row
  const char* Abase = (const char*)A;
  const char* Bbase = (const char*)B;

  for (int kk = 0; kk < nk; ++kk) {
    const size_t kb = (size_t)kk * 64;  // byte offset within row
    uint4 a0 = *(const uint4*)(Abase + ((size_t)(bm * 128 + srow) * K) * 2 + kb + sj * 16);
    uint4 a1 = *(const uint4*)(Abase + ((size_t)(bm * 128 + srow + 64) * K) * 2 + kb + sj * 16);
    uint4 b0 = *(const uint4*)(Bbase + ((size_t)(bn * 128 + srow) * K) * 2 + kb + sj * 16);
    uint4 b1 = *(const uint4*)(Bbase + ((size_t)(bn * 128 + srow + 64) * K) * 2 + kb + sj * 16);
    __syncthreads();
    const int sw0 = (sj * 16) ^ (((srow >> 1) & 3) << 4);
    const int sw1 = (sj * 16) ^ ((((srow + 64) >> 1) & 3) << 4);
    *(uint4*)((char*)As + srow * 64 + sw0) = a0;
    *(uint4*)((char*)As + (srow + 64) * 64 + sw1) = a1;
    *(uint4*)((char*)Bs + srow * 64 + sw0) = b0;
    *(uint4*)((char*)Bs + (srow + 64) * 64 + sw1) = b1;
    __syncthreads();
    short8 af[4], bfr[4];
#pragma unroll
    for (int m = 0; m < 4; ++m) {
      int row = wr * 64 + m * 16 + c;
      af[m] = ldfrag((const char*)As + row * 64 + ((g * 16) ^ (((row >> 1) & 3) << 4)));
    }
#pragma unroll
    for (int n = 0; n < 4; ++n) {
      int row = wc * 64 + n * 16 + c;
      bfr[n] = ldfrag((const char*)Bs + row * 64 + ((g * 16) ^ (((row >> 1) & 3) << 4)));
    }
#pragma unroll
    for (int m = 0; m < 4; ++m)
#pragma unroll
      for (int n = 0; n < 4; ++n) acc[m][n] = MFMA16(af[m], bfr[n], acc[m][n]);
  }

  const int row0 = bm * 128 + wr * 64 + 4 * g;
  const int col0 = bn * 128 + wc * 64 + c;
#pragma unroll
  for (int m = 0; m < 4; ++m) {
#pragma unroll
    for (int n = 0; n < 4; ++n) {
      const int row = row0 + m * 16;
      const int col = col0 + n * 16;
      if (EPI == 0) {
#pragma unroll
        for (int rr = 0; rr < 4; ++rr)
          ((u16*)out)[(size_t)(row + rr) * N + col] = f2b(acc[m][n][rr]);
      } else if (EPI == 1) {
        ushort4 o = { f2b(acc[m][n][0]), f2b(acc[m][n][1]), f2b(acc[m][n][2]), f2b(acc[m][n][3]) };
        *(ushort4*)((u16*)out + (size_t)col * M + row) = o;
      } else if (EPI == 2) {
        float bc = bias[col];
#pragma unroll
        for (int rr = 0; rr < 4; ++rr) {
          size_t idx = (size_t)(row + rr) * N + col;
          ((float*)out)[idx] = acc[m][n][rr] + bc + resid[idx];
        }
      } else {
        float bc = bias[col];
#pragma unroll
        for (int rr = 0; rr < 4; ++rr)
          ((u16*)out)[(size_t)(row + rr) * N + col] = f2b(gelu_exact(acc[m][n][rr] + bc));
      }
    }
  }
}

// ---------------- Flash attention: 8 heads, d_head=256, N=4096 ----------------
// Q [4096][2048] bf16, K [4096][2048] bf16, VT [2048][4096] bf16 -> attn [4096][2048] bf16
__global__ __launch_bounds__(512, 1) void k_attn(const u16* __restrict__ Q,
                                                 const u16* __restrict__ Km,
                                                 const u16* __restrict__ VT,
                                                 u16* __restrict__ out) {
  __shared__ __attribute__((aligned(16))) u16 Klds[32 * 256];   // [kv 32][d 256], swizzled
  __shared__ __attribute__((aligned(16))) u16 Vlds[256 * 32];   // [d 256][kv 32], swizzled
  __shared__ __attribute__((aligned(16))) u16 Plds[8 * 16 * 40];  // per-wave [16 q][32 kv], pad to 40
  const int t = threadIdx.x;
  const int w = t >> 6, l = t & 63, g = l >> 4, c = l & 15;
  const int head = blockIdx.x, qb = blockIdx.y;

  short8 aq[8];
  {
    const char* qp = (const char*)Q + (size_t)(qb * 128 + w * 16 + c) * 4096 + head * 512 + g * 16;
#pragma unroll
    for (int dc = 0; dc < 8; ++dc) aq[dc] = ldfrag(qp + dc * 64);
  }
  f32x4 o[16] = {};
  float mrun[4] = { -__builtin_inff(), -__builtin_inff(), -__builtin_inff(), -__builtin_inff() };
  float lsum[4] = {};

  u16* Pw = Plds + w * 640;

  const int ks_row = t >> 5, ks_j = t & 31;  // K chunk: 1024 slots of 16B, 2/thread
  const int vs_row = t >> 2, vs_j = t & 3;   // VT chunk: 1024 slots of 16B, 2/thread
  const char* Kbase = (const char*)Km + head * 512;
  const char* Vbase = (const char*)VT + (size_t)head * 256 * 8192;

  for (int kv0 = 0; kv0 < 4096; kv0 += 32) {
    uint4 kld0 = *(const uint4*)(Kbase + (size_t)(kv0 + ks_row) * 4096 + ks_j * 16);
    uint4 kld1 = *(const uint4*)(Kbase + (size_t)(kv0 + 16 + ks_row) * 4096 + ks_j * 16);
    uint4 vld0 = *(const uint4*)(Vbase + (size_t)vs_row * 8192 + kv0 * 2 + vs_j * 16);
    uint4 vld1 = *(const uint4*)(Vbase + (size_t)(vs_row + 128) * 8192 + kv0 * 2 + vs_j * 16);
    __syncthreads();
    *(uint4*)((char*)Klds + ks_row * 512 + ((ks_j * 16) ^ ((ks_row & 7) << 4))) = kld0;
    *(uint4*)((char*)Klds + (ks_row + 16) * 512 + ((ks_j * 16) ^ (((ks_row + 16) & 7) << 4))) = kld1;
    *(uint4*)((char*)Vlds + vs_row * 64 + ((vs_j * 16) ^ (((vs_row >> 1) & 3) << 4))) = vld0;
    *(uint4*)((char*)Vlds + (vs_row + 128) * 64 + ((vs_j * 16) ^ ((((vs_row + 128) >> 1) & 3) << 4))) = vld1;
    __syncthreads();

    // S = Q K^T  (two 16x16 kv tiles)
    f32x4 s0 = {}, s1 = {};
#pragma unroll
    for (int dc = 0; dc < 8; ++dc) {
      const int dbyte = dc * 64 + g * 16;
      short8 bk0 = ldfrag((const char*)Klds + (size_t)c * 512 + (dbyte ^ ((c & 7) << 4)));
      short8 bk1 = ldfrag((const char*)Klds + (size_t)(16 + c) * 512 + (dbyte ^ ((c & 7) << 4)));
      s0 = MFMA16(aq[dc], bk0, s0);
      s1 = MFMA16(aq[dc], bk1, s1);
    }
    float p0[4], p1[4], pm[4], scl[4], rs[4];
#pragma unroll
    for (int rr = 0; rr < 4; ++rr) {
      p0[rr] = s0[rr] * 0.0625f;
      p1[rr] = s1[rr] * 0.0625f;
      pm[rr] = fmaxf(p0[rr], p1[rr]);
    }
#pragma unroll
    for (int rr = 0; rr < 4; ++rr) {
#pragma unroll
      for (int m = 1; m < 16; m <<= 1) pm[rr] = fmaxf(pm[rr], __shfl_xor(pm[rr], m));
      float mn = fmaxf(mrun[rr], pm[rr]);
      scl[rr] = __expf(mrun[rr] - mn);
      mrun[rr] = mn;
      p0[rr] = __expf(p0[rr] - mn);
      p1[rr] = __expf(p1[rr] - mn);
      rs[rr] = p0[rr] + p1[rr];
#pragma unroll
      for (int m = 1; m < 16; m <<= 1) rs[rr] += __shfl_xor(rs[rr], m);
      lsum[rr] = lsum[rr] * scl[rr] + rs[rr];
    }
#pragma unroll
    for (int dt = 0; dt < 16; ++dt)
#pragma unroll
      for (int rr = 0; rr < 4; ++rr) o[dt][rr] *= scl[rr];

    // P -> per-wave LDS -> A-fragment
#pragma unroll
    for (int rr = 0; rr < 4; ++rr) {
      Pw[(4 * g + rr) * 40 + c] = f2b(p0[rr]);
      Pw[(4 * g + rr) * 40 + 16 + c] = f2b(p1[rr]);
    }
    __builtin_amdgcn_sched_barrier(0);
    short8 pa = ldfrag((const char*)Pw + c * 80 + g * 16);

#pragma unroll
    for (int dt = 0; dt < 16; ++dt) {
      const int row = dt * 16 + c;
      short8 bv = ldfrag((const char*)Vlds + row * 64 + ((g * 16) ^ (((row >> 1) & 3) << 4)));
      o[dt] = MFMA16(pa, bv, o[dt]);
    }
  }

  float inv[4];
#pragma unroll
  for (int rr = 0; rr < 4; ++rr) inv[rr] = 1.0f / lsum[rr];
  u16* orow = out + (size_t)(qb * 128 + w * 16 + 4 * g) * 2048 + head * 256 + c;
#pragma unroll
  for (int dt = 0; dt < 16; ++dt)
#pragma unroll
    for (int rr = 0; rr < 4; ++rr)
      orow[(size_t)rr * 2048 + dt * 16] = f2b(o[dt][rr] * inv[rr]);
}

// ---------------- launch ----------------
extern "C" void kernel_launch(void* const* d_in, const int* in_sizes, int n_in,
                              void* d_out, int out_size, void* d_ws, size_t ws_size,
                              hipStream_t stream) {
  const float* x   = (const float*)d_in[0];
  const float* Wq  = (const float*)d_in[1];
  const float* Wk  = (const float*)d_in[2];
  const float* Wv  = (const float*)d_in[3];
  const float* Wo  = (const float*)d_in[4];
  const float* bo  = (const float*)d_in[5];
  const float* g1  = (const float*)d_in[6];
  const float* be1 = (const float*)d_in[7];
  const float* g2  = (const float*)d_in[8];
  const float* be2 = (const float*)d_in[9];
  const float* W1  = (const float*)d_in[10];
  const float* b1  = (const float*)d_in[11];
  const float* W2  = (const float*)d_in[12];
  const float* b2  = (const float*)d_in[13];

  char* ws = (char*)d_ws;
  size_t off = 0;
  auto alloc = [&](size_t n) {
    char* p = ws + off;
    off = (off + n + 255) & ~(size_t)255;
    return p;
  };
  u16* hb    = (u16*)alloc(4096 * 256 * 2);
  u16* Wqb   = (u16*)alloc(2048 * 256 * 2);
  u16* Wkb   = (u16*)alloc(2048 * 256 * 2);
  u16* Wvb   = (u16*)alloc(2048 * 256 * 2);
  u16* Wob   = (u16*)alloc(256 * 2048 * 2);
  u16* W1b   = (u16*)alloc(1024 * 256 * 2);
  u16* W2b   = (u16*)alloc(256 * 1024 * 2);
  u16* Qb    = (u16*)alloc((size_t)4096 * 2048 * 2);
  u16* Kb    = (u16*)alloc((size_t)4096 * 2048 * 2);
  u16* VTb   = (u16*)alloc((size_t)2048 * 4096 * 2);
  u16* attnb = (u16*)alloc((size_t)4096 * 2048 * 2);
  float* x2  = (float*)alloc(4096 * 256 * 4);
  u16* h2b   = (u16*)alloc(4096 * 256 * 2);
  u16* ffn1  = (u16*)alloc((size_t)4096 * 1024 * 2);

  k_f2b<<<512, 256, 0, stream>>>(Wq, Wqb, 131072);
  k_f2b<<<512, 256, 0, stream>>>(Wk, Wkb, 131072);
  k_f2b<<<512, 256, 0, stream>>>(Wv, Wvb, 131072);
  k_f2b<<<512, 256, 0, stream>>>(Wo, Wob, 131072);
  k_f2b<<<256, 256, 0, stream>>>(W1, W1b, 65536);
  k_f2b<<<256, 256, 0, stream>>>(W2, W2b, 65536);

  k_ln<<<1024, 256, 0, stream>>>(x, g1, be1, hb);

  k_gemm<0><<<dim3(16, 32), 256, 0, stream>>>(hb, Wqb, Qb, nullptr, nullptr, 4096, 2048, 256);
  k_gemm<0><<<dim3(16, 32), 256, 0, stream>>>(hb, Wkb, Kb, nullptr, nullptr, 4096, 2048, 256);
  k_gemm<1><<<dim3(16, 32), 256, 0, stream>>>(hb, Wvb, VTb, nullptr, nullptr, 4096, 2048, 256);

  k_attn<<<dim3(8, 32), 512, 0, stream>>>(Qb, Kb, VTb, attnb);

  k_gemm<2><<<dim3(2, 32), 256, 0, stream>>>(attnb, Wob, x2, bo, x, 4096, 256, 2048);
  k_ln<<<1024, 256, 0, stream>>>(x2, g2, be2, h2b);
  k_gemm<3><<<dim3(8, 32), 256, 0, stream>>>(h2b, W1b, ffn1, b1, nullptr, 4096, 1024, 256);
  k_gemm<2><<<dim3(2, 32), 256, 0, stream>>>(ffn1, W2b, (float*)d_out, b2, x2, 4096, 256, 1024);
}

// Round 3
// 304.506 us; speedup vs baseline: 1.4083x; 1.4083x over previous
//
#include <hip/hip_runtime.h>

typedef __attribute__((ext_vector_type(8))) short short8;
typedef __attribute__((ext_vector_type(4))) float f32x4;
typedef __attribute__((ext_vector_type(16))) float f32x16;
typedef unsigned short u16;
typedef unsigned int u32;

#define DEVFN static __device__ __forceinline__

DEVFN u16 f2b(float f) {
  u32 u = __builtin_bit_cast(u32, f);
  u32 r = u + 0x7fffu + ((u >> 16) & 1u);
  return (u16)(r >> 16);
}

DEVFN short8 ldfrag(const void* p) {
  return __builtin_bit_cast(short8, *(const uint4*)p);
}

#define MFMA16(a, b, c) __builtin_amdgcn_mfma_f32_16x16x32_bf16((a), (b), (c), 0, 0, 0)
#define MFMA32(a, b, c) __builtin_amdgcn_mfma_f32_32x32x16_bf16((a), (b), (c), 0, 0, 0)
#define EXP2(x) __builtin_amdgcn_exp2f(x)

DEVFN void llds16(const void* g, void* l) {
  __builtin_amdgcn_global_load_lds((const __attribute__((address_space(1))) void*)g,
                                   (__attribute__((address_space(3))) void*)l, 16, 0, 0);
}

DEVFN float gelu_exact(float v) {
  return 0.5f * v * (1.0f + erff(v * 0.70710678118654752f));
}

// ---------------- f32 -> bf16 convert ----------------
__global__ void k_f2b(const float* __restrict__ in, u16* __restrict__ out, int n4) {
  int i = blockIdx.x * 256 + threadIdx.x;
  if (i >= n4) return;
  float4 v = ((const float4*)in)[i];
  ushort4 o = { f2b(v.x), f2b(v.y), f2b(v.z), f2b(v.w) };
  ((ushort4*)out)[i] = o;
}

// ---------------- LayerNorm (256 cols), f32 in -> bf16 out ----------------
__global__ __launch_bounds__(256) void k_ln(const float* __restrict__ x,
                                            const float* __restrict__ g,
                                            const float* __restrict__ b,
                                            u16* __restrict__ out) {
  int row = blockIdx.x * 4 + (threadIdx.x >> 6);
  int l = threadIdx.x & 63;
  const float4 v = *(const float4*)(x + (size_t)row * 256 + l * 4);
  float s = v.x + v.y + v.z + v.w;
#pragma unroll
  for (int m = 1; m < 64; m <<= 1) s += __shfl_xor(s, m);
  float mu = s * (1.0f / 256.0f);
  float dx = v.x - mu, dy = v.y - mu, dz = v.z - mu, dw = v.w - mu;
  float q = dx * dx + dy * dy + dz * dz + dw * dw;
#pragma unroll
  for (int m = 1; m < 64; m <<= 1) q += __shfl_xor(q, m);
  float r = rsqrtf(q * (1.0f / 256.0f) + 1e-5f);
  float4 gv = *(const float4*)(g + l * 4);
  float4 bv = *(const float4*)(b + l * 4);
  ushort4 o = { f2b(dx * r * gv.x + bv.x), f2b(dy * r * gv.y + bv.y),
                f2b(dz * r * gv.z + bv.z), f2b(dw * r * gv.w + bv.w) };
  *(ushort4*)(out + (size_t)row * 256 + l * 4) = o;
}

// ---------------- GEMM: C[M,N] = A[M,K] * B[N,K]^T, bf16 inputs ----------------
// EPI 0: bf16 store            EPI 1: bf16 transposed store (out[col*M+row])
// EPI 2: f32 + bias + resid    EPI 3: bf16 + bias + GELU    EPI 4: f32 partial (split-K over gridDim.z)
template <int EPI>
__global__ __launch_bounds__(256, 2) void k_gemm(const u16* __restrict__ A,
                                                 const u16* __restrict__ B,
                                                 void* __restrict__ out,
                                                 const float* __restrict__ bias,
                                                 const float* __restrict__ resid,
                                                 int M, int N, int K) {
  __shared__ __attribute__((aligned(16))) u16 As[128 * 32];
  __shared__ __attribute__((aligned(16))) u16 Bs[128 * 32];
  const int t = threadIdx.x;
  const int w = t >> 6, l = t & 63, g = l >> 4, c = l & 15;
  const int wr = w >> 1, wc = w & 1;
  const int bm = blockIdx.y, bn = blockIdx.x;

  f32x4 acc[4][4] = {};
  int nk = K >> 5, kk0 = 0;
  if (EPI == 4) { nk = nk / gridDim.z; kk0 = blockIdx.z * nk; }

  const int srow = t >> 2;
  const int sj = t & 3;
  const char* Abase = (const char*)A;
  const char* Bbase = (const char*)B;

  for (int kk = kk0; kk < kk0 + nk; ++kk) {
    const size_t kb = (size_t)kk * 64;
    uint4 a0 = *(const uint4*)(Abase + ((size_t)(bm * 128 + srow) * K) * 2 + kb + sj * 16);
    uint4 a1 = *(const uint4*)(Abase + ((size_t)(bm * 128 + srow + 64) * K) * 2 + kb + sj * 16);
    uint4 b0 = *(const uint4*)(Bbase + ((size_t)(bn * 128 + srow) * K) * 2 + kb + sj * 16);
    uint4 b1 = *(const uint4*)(Bbase + ((size_t)(bn * 128 + srow + 64) * K) * 2 + kb + sj * 16);
    __syncthreads();
    const int sw0 = (sj * 16) ^ (((srow >> 1) & 3) << 4);
    const int sw1 = (sj * 16) ^ ((((srow + 64) >> 1) & 3) << 4);
    *(uint4*)((char*)As + srow * 64 + sw0) = a0;
    *(uint4*)((char*)As + (srow + 64) * 64 + sw1) = a1;
    *(uint4*)((char*)Bs + srow * 64 + sw0) = b0;
    *(uint4*)((char*)Bs + (srow + 64) * 64 + sw1) = b1;
    __syncthreads();
    short8 af[4], bfr[4];
#pragma unroll
    for (int m = 0; m < 4; ++m) {
      int row = wr * 64 + m * 16 + c;
      af[m] = ldfrag((const char*)As + row * 64 + ((g * 16) ^ (((row >> 1) & 3) << 4)));
    }
#pragma unroll
    for (int n = 0; n < 4; ++n) {
      int row = wc * 64 + n * 16 + c;
      bfr[n] = ldfrag((const char*)Bs + row * 64 + ((g * 16) ^ (((row >> 1) & 3) << 4)));
    }
#pragma unroll
    for (int m = 0; m < 4; ++m)
#pragma unroll
      for (int n = 0; n < 4; ++n) acc[m][n] = MFMA16(af[m], bfr[n], acc[m][n]);
  }

  const int row0 = bm * 128 + wr * 64 + 4 * g;
  const int col0 = bn * 128 + wc * 64 + c;
#pragma unroll
  for (int m = 0; m < 4; ++m) {
#pragma unroll
    for (int n = 0; n < 4; ++n) {
      const int row = row0 + m * 16;
      const int col = col0 + n * 16;
      if (EPI == 0) {
#pragma unroll
        for (int rr = 0; rr < 4; ++rr)
          ((u16*)out)[(size_t)(row + rr) * N + col] = f2b(acc[m][n][rr]);
      } else if (EPI == 1) {
        ushort4 o = { f2b(acc[m][n][0]), f2b(acc[m][n][1]), f2b(acc[m][n][2]), f2b(acc[m][n][3]) };
        *(ushort4*)((u16*)out + (size_t)col * M + row) = o;
      } else if (EPI == 2) {
        float bc = bias[col];
#pragma unroll
        for (int rr = 0; rr < 4; ++rr) {
          size_t idx = (size_t)(row + rr) * N + col;
          ((float*)out)[idx] = acc[m][n][rr] + bc + resid[idx];
        }
      } else if (EPI == 3) {
        float bc = bias[col];
#pragma unroll
        for (int rr = 0; rr < 4; ++rr)
          ((u16*)out)[(size_t)(row + rr) * N + col] = f2b(gelu_exact(acc[m][n][rr] + bc));
      } else {
        float* po = (float*)out + (size_t)blockIdx.z * M * N;
#pragma unroll
        for (int rr = 0; rr < 4; ++rr)
          po[(size_t)(row + rr) * N + col] = acc[m][n][rr];
      }
    }
  }
}

// ---------------- reduce 4 split-K partials + bias + residual -> f32 ----------------
__global__ __launch_bounds__(256) void k_red4(const float* __restrict__ p,
                                              const float* __restrict__ bias,
                                              const float* __restrict__ resid,
                                              float* __restrict__ out) {
  int i = blockIdx.x * 256 + threadIdx.x;  // 262144 float4 elements (4096*256/4)
  const float4* p4 = (const float4*)p;
  float4 a = p4[i], b = p4[i + 262144], c = p4[i + 524288], d = p4[i + 786432];
  float4 r = ((const float4*)resid)[i];
  float4 bb = ((const float4*)bias)[i & 63];
  float4 o;
  o.x = a.x + b.x + c.x + d.x + r.x + bb.x;
  o.y = a.y + b.y + c.y + d.y + r.y + bb.y;
  o.z = a.z + b.z + c.z + d.z + r.z + bb.z;
  o.w = a.w + b.w + c.w + d.w + r.w + bb.w;
  ((float4*)out)[i] = o;
}

// ---------------- Flash attention: 8 heads, d_head=256, N=4096 ----------------
// 32x32x16 MFMA, swapped QK^T (A=K,B=Q), 4 waves x 32 q-rows, KVBLK=64, dbuf LDS via global_load_lds.
// Q [4096][2048] bf16, K [4096][2048] bf16, VT [2048][4096] bf16 -> attn [4096][2048] bf16
__global__ __launch_bounds__(256, 1) void k_attn(const u16* __restrict__ Q,
                                                 const u16* __restrict__ Km,
                                                 const u16* __restrict__ VT,
                                                 u16* __restrict__ out) {
  // K0 @0 (32KB), K1 @32768, V0 @65536, V1 @98304, P @131072 (16KB) = 144KB
  __shared__ __attribute__((aligned(16))) char smem[147456];
  const int t = threadIdx.x;
  const int w = t >> 6, l = t & 63;
  const int q31 = l & 31, hi = l >> 5;
  const int head = blockIdx.x, qb = blockIdx.y;
  const float C2 = 0.0625f * 1.44269504f;  // 1/sqrt(256) * log2(e)

  // Q as B-fragments (reg-resident): B[k][n]: n=q31, k=ks*16+hi*8+j
  short8 qf[16];
  {
    const char* qp = (const char*)Q + (size_t)(qb * 128 + w * 32 + q31) * 4096 + head * 512 + hi * 16;
#pragma unroll
    for (int ks = 0; ks < 16; ++ks) qf[ks] = ldfrag(qp + ks * 32);
  }

  f32x16 o[8] = {};
  float m = -1e30f, lsum = 0.0f;

  const char* KbaseH = (const char*)Km + head * 512;
  const char* VbaseH = (const char*)VT + (size_t)head * 256 * 8192;
  char* Pp = smem + 131072 + w * 4096;  // per-wave P: [32 q][64 kv] bf16, XOR-swizzled

  auto stage = [&](int c) {
    const int buf = c & 1;
    const int kv0 = c * 64;
    char* kd = smem + buf * 32768;
    char* vd = smem + 65536 + buf * 32768;
#pragma unroll
    for (int ii = 0; ii < 8; ++ii) {
      const int i = w * 8 + ii;
      const int row = 2 * i + hi;  // K LDS row (kv), slot q31; inverse-swizzled source
      const char* g = KbaseH + (size_t)(kv0 + row) * 4096 + ((q31 ^ row) << 4);
      llds16(g, kd + i * 1024);
    }
#pragma unroll
    for (int ii = 0; ii < 8; ++ii) {
      const int i = w * 8 + ii;
      const int row = 8 * i + (l >> 3);  // V LDS row (d), slot l&7
      const char* g = VbaseH + (size_t)row * 8192 + kv0 * 2 + (((l & 7) ^ (row & 7)) << 4);
      llds16(g, vd + i * 1024);
    }
  };

  stage(0);
  for (int c = 0; c < 64; ++c) {
    const int buf = c & 1;
    asm volatile("s_waitcnt vmcnt(0)" ::: "memory");
    __builtin_amdgcn_s_barrier();
    __builtin_amdgcn_sched_barrier(0);
    if (c < 63) stage(c + 1);

    const char* kd = smem + buf * 32768;
    const char* vd = smem + 65536 + buf * 32768;

    // S^T = K . Q^T : C[kv][q], two 32-kv tiles
    f32x16 s0 = {}, s1 = {};
    const char* ka0 = kd + q31 * 512;
    const char* ka1 = kd + (32 + q31) * 512;
    const int sswz = q31 << 4;
#pragma unroll
    for (int ks = 0; ks < 16; ++ks) {
      const int rb = ks * 32 + hi * 16;
      short8 a0 = ldfrag(ka0 + (rb ^ sswz));
      short8 a1 = ldfrag(ka1 + (rb ^ sswz));
      s0 = MFMA32(a0, qf[ks], s0);
      s1 = MFMA32(a1, qf[ks], s1);
    }

    // online softmax over kv (lane-local 32 values + xor32), defer-max
    float pm = s0[0];
#pragma unroll
    for (int i = 1; i < 16; ++i) pm = fmaxf(pm, s0[i]);
#pragma unroll
    for (int i = 0; i < 16; ++i) pm = fmaxf(pm, s1[i]);
    pm = fmaxf(pm, __shfl_xor(pm, 32));
    if (__any(pm > m + 64.0f)) {
      float mn = fmaxf(m, pm);
      float sc = EXP2((m - mn) * C2);
      m = mn;
      lsum *= sc;
#pragma unroll
      for (int i = 0; i < 16; ++i) {
        const int r = (i & 3) + 8 * (i >> 2) + 4 * hi;
        float sclr = __shfl(sc, r);
#pragma unroll
        for (int dt = 0; dt < 8; ++dt) o[dt][i] *= sclr;
      }
    }
    const float mc2 = m * C2;
    float p0[16], p1[16];
    float rs = 0.f;
#pragma unroll
    for (int i = 0; i < 16; ++i) { p0[i] = EXP2(fmaf(s0[i], C2, -mc2)); rs += p0[i]; }
#pragma unroll
    for (int i = 0; i < 16; ++i) { p1[i] = EXP2(fmaf(s1[i], C2, -mc2)); rs += p1[i]; }
    rs += __shfl_xor(rs, 32);
    lsum += rs;

    // P -> per-wave LDS [q][kv], b64 packed writes (4 consecutive kv per group)
    const int pswz = (q31 & 7) << 4;
    char* prow = Pp + q31 * 128;
#pragma unroll
    for (int g4 = 0; g4 < 4; ++g4) {
      ushort4 w0 = { f2b(p0[g4 * 4 + 0]), f2b(p0[g4 * 4 + 1]), f2b(p0[g4 * 4 + 2]), f2b(p0[g4 * 4 + 3]) };
      ushort4 w1 = { f2b(p1[g4 * 4 + 0]), f2b(p1[g4 * 4 + 1]), f2b(p1[g4 * 4 + 2]), f2b(p1[g4 * 4 + 3]) };
      *(ushort4*)(prow + ((g4 * 16 + hi * 8) ^ pswz)) = w0;
      *(ushort4*)(prow + ((64 + g4 * 16 + hi * 8) ^ pswz)) = w1;
    }

    // O += P . V : A=P[32q][16kv] frags (reused over 8 d-tiles), B=V[16kv][32d]
    short8 pa[4];
#pragma unroll
    for (int ks = 0; ks < 4; ++ks)
      pa[ks] = ldfrag(prow + ((ks * 32 + hi * 16) ^ pswz));
#pragma unroll
    for (int dt = 0; dt < 8; ++dt) {
      const char* vrow = vd + (dt * 32 + q31) * 128;
#pragma unroll
      for (int ks = 0; ks < 4; ++ks) {
        short8 bv = ldfrag(vrow + ((ks * 32 + hi * 16) ^ pswz));
        o[dt] = MFMA32(pa[ks], bv, o[dt]);
      }
    }
  }

  float invl = 1.0f / lsum;
#pragma unroll
  for (int i = 0; i < 16; ++i) {
    const int r = (i & 3) + 8 * (i >> 2) + 4 * hi;
    float invr = __shfl(invl, r);
    const size_t qg = (size_t)(qb * 128 + w * 32 + r);
#pragma unroll
    for (int dt = 0; dt < 8; ++dt)
      out[qg * 2048 + head * 256 + dt * 32 + q31] = f2b(o[dt][i] * invr);
  }
}

// ---------------- launch ----------------
extern "C" void kernel_launch(void* const* d_in, const int* in_sizes, int n_in,
                              void* d_out, int out_size, void* d_ws, size_t ws_size,
                              hipStream_t stream) {
  const float* x   = (const float*)d_in[0];
  const float* Wq  = (const float*)d_in[1];
  const float* Wk  = (const float*)d_in[2];
  const float* Wv  = (const float*)d_in[3];
  const float* Wo  = (const float*)d_in[4];
  const float* bo  = (const float*)d_in[5];
  const float* g1  = (const float*)d_in[6];
  const float* be1 = (const float*)d_in[7];
  const float* g2  = (const float*)d_in[8];
  const float* be2 = (const float*)d_in[9];
  const float* W1  = (const float*)d_in[10];
  const float* b1  = (const float*)d_in[11];
  const float* W2  = (const float*)d_in[12];
  const float* b2  = (const float*)d_in[13];

  char* ws = (char*)d_ws;
  size_t off = 0;
  auto alloc = [&](size_t n) {
    char* p = ws + off;
    off = (off + n + 255) & ~(size_t)255;
    return p;
  };
  u16* hb    = (u16*)alloc(4096 * 256 * 2);
  u16* Wqb   = (u16*)alloc(2048 * 256 * 2);
  u16* Wkb   = (u16*)alloc(2048 * 256 * 2);
  u16* Wvb   = (u16*)alloc(2048 * 256 * 2);
  u16* Wob   = (u16*)alloc(256 * 2048 * 2);
  u16* W1b   = (u16*)alloc(1024 * 256 * 2);
  u16* W2b   = (u16*)alloc(256 * 1024 * 2);
  u16* Qb    = (u16*)alloc((size_t)4096 * 2048 * 2);
  u16* Kb    = (u16*)alloc((size_t)4096 * 2048 * 2);
  u16* VTb   = (u16*)alloc((size_t)2048 * 4096 * 2);
  u16* attnb = (u16*)alloc((size_t)4096 * 2048 * 2);
  float* x2  = (float*)alloc(4096 * 256 * 4);
  u16* h2b   = (u16*)alloc(4096 * 256 * 2);
  u16* ffn1  = (u16*)alloc((size_t)4096 * 1024 * 2);
  float* pbuf = (float*)Qb;  // 16MB, dead after k_attn: holds 4x [4096][256] f32 partials

  k_f2b<<<512, 256, 0, stream>>>(Wq, Wqb, 131072);
  k_f2b<<<512, 256, 0, stream>>>(Wk, Wkb, 131072);
  k_f2b<<<512, 256, 0, stream>>>(Wv, Wvb, 131072);
  k_f2b<<<512, 256, 0, stream>>>(Wo, Wob, 131072);
  k_f2b<<<256, 256, 0, stream>>>(W1, W1b, 65536);
  k_f2b<<<256, 256, 0, stream>>>(W2, W2b, 65536);

  k_ln<<<1024, 256, 0, stream>>>(x, g1, be1, hb);

  k_gemm<0><<<dim3(16, 32), 256, 0, stream>>>(hb, Wqb, Qb, nullptr, nullptr, 4096, 2048, 256);
  k_gemm<0><<<dim3(16, 32), 256, 0, stream>>>(hb, Wkb, Kb, nullptr, nullptr, 4096, 2048, 256);
  k_gemm<1><<<dim3(16, 32), 256, 0, stream>>>(hb, Wvb, VTb, nullptr, nullptr, 4096, 2048, 256);

  k_attn<<<dim3(8, 32), 256, 0, stream>>>(Qb, Kb, VTb, attnb);

  k_gemm<4><<<dim3(2, 32, 4), 256, 0, stream>>>(attnb, Wob, pbuf, nullptr, nullptr, 4096, 256, 2048);
  k_red4<<<1024, 256, 0, stream>>>(pbuf, bo, x, x2);
  k_ln<<<1024, 256, 0, stream>>>(x2, g2, be2, h2b);
  k_gemm<3><<<dim3(8, 32), 256, 0, stream>>>(h2b, W1b, ffn1, b1, nullptr, 4096, 1024, 256);
  k_gemm<4><<<dim3(2, 32, 4), 256, 0, stream>>>(ffn1, W2b, pbuf, nullptr, nullptr, 4096, 256, 1024);
  k_red4<<<1024, 256, 0, stream>>>(pbuf, b2, x2, (float*)d_out);
}

// Round 4
// 278.952 us; speedup vs baseline: 1.5373x; 1.0916x over previous
//
#include <hip/hip_runtime.h>

typedef __attribute__((ext_vector_type(8))) short short8;
typedef __attribute__((ext_vector_type(4))) float f32x4;
typedef __attribute__((ext_vector_type(16))) float f32x16;
typedef unsigned short u16;
typedef unsigned int u32;

#define DEVFN static __device__ __forceinline__

DEVFN u16 f2b(float f) {
  u32 u = __builtin_bit_cast(u32, f);
  u32 r = u + 0x7fffu + ((u >> 16) & 1u);
  return (u16)(r >> 16);
}

DEVFN float b2f(u16 b) {
  u32 u = ((u32)b) << 16;
  return __builtin_bit_cast(float, u);
}

DEVFN short8 ldfrag(const void* p) {
  return __builtin_bit_cast(short8, *(const uint4*)p);
}

#define MFMA16(a, b, c) __builtin_amdgcn_mfma_f32_16x16x32_bf16((a), (b), (c), 0, 0, 0)
#define MFMA32(a, b, c) __builtin_amdgcn_mfma_f32_32x32x16_bf16((a), (b), (c), 0, 0, 0)
#define EXP2(x) __builtin_amdgcn_exp2f(x)

DEVFN void llds16(const void* g, void* l) {
  __builtin_amdgcn_global_load_lds((const __attribute__((address_space(1))) void*)g,
                                   (__attribute__((address_space(3))) void*)l, 16, 0, 0);
}

DEVFN float gelu_exact(float v) {
  return 0.5f * v * (1.0f + erff(v * 0.70710678118654752f));
}

// ---------------- merged f32 -> bf16 weight convert ----------------
__global__ void k_f2bm(const float* s0, const float* s1, const float* s2,
                       const float* s3, const float* s4, const float* s5,
                       u16* d0, u16* d1, u16* d2, u16* d3, u16* d4, u16* d5) {
  int i = blockIdx.x * 256 + threadIdx.x;
  const float* s;
  u16* d;
  int n4;
  switch (blockIdx.y) {
    case 0: s = s0; d = d0; n4 = 131072; break;
    case 1: s = s1; d = d1; n4 = 131072; break;
    case 2: s = s2; d = d2; n4 = 131072; break;
    case 3: s = s3; d = d3; n4 = 131072; break;
    case 4: s = s4; d = d4; n4 = 65536; break;
    default: s = s5; d = d5; n4 = 65536; break;
  }
  if (i >= n4) return;
  float4 v = ((const float4*)s)[i];
  ushort4 o = { f2b(v.x), f2b(v.y), f2b(v.z), f2b(v.w) };
  ((ushort4*)d)[i] = o;
}

// ---------------- LayerNorm (256 cols), f32 in -> bf16 out ----------------
__global__ __launch_bounds__(256) void k_ln(const float* __restrict__ x,
                                            const float* __restrict__ g,
                                            const float* __restrict__ b,
                                            u16* __restrict__ out) {
  int row = blockIdx.x * 4 + (threadIdx.x >> 6);
  int l = threadIdx.x & 63;
  const float4 v = *(const float4*)(x + (size_t)row * 256 + l * 4);
  float s = v.x + v.y + v.z + v.w;
#pragma unroll
  for (int m = 1; m < 64; m <<= 1) s += __shfl_xor(s, m);
  float mu = s * (1.0f / 256.0f);
  float dx = v.x - mu, dy = v.y - mu, dz = v.z - mu, dw = v.w - mu;
  float q = dx * dx + dy * dy + dz * dz + dw * dw;
#pragma unroll
  for (int m = 1; m < 64; m <<= 1) q += __shfl_xor(q, m);
  float r = rsqrtf(q * (1.0f / 256.0f) + 1e-5f);
  float4 gv = *(const float4*)(g + l * 4);
  float4 bv = *(const float4*)(b + l * 4);
  ushort4 o = { f2b(dx * r * gv.x + bv.x), f2b(dy * r * gv.y + bv.y),
                f2b(dz * r * gv.z + bv.z), f2b(dw * r * gv.w + bv.w) };
  *(ushort4*)(out + (size_t)row * 256 + l * 4) = o;
}

// ---------------- GEMM: C[M,N] = A[M,K] * B[N,K]^T, bf16 inputs ----------------
// EPI 0: bf16 store            EPI 1: bf16 transposed store (out[col*M+row])
// EPI 2: f32 + bias + resid    EPI 3: bf16 + bias + GELU    EPI 4: f32 partial (split-K over gridDim.z)
template <int EPI>
__global__ __launch_bounds__(256, 2) void k_gemm(const u16* __restrict__ A,
                                                 const u16* __restrict__ B,
                                                 void* __restrict__ out,
                                                 const float* __restrict__ bias,
                                                 const float* __restrict__ resid,
                                                 int M, int N, int K) {
  __shared__ __attribute__((aligned(16))) u16 As[128 * 32];
  __shared__ __attribute__((aligned(16))) u16 Bs[128 * 32];
  const int t = threadIdx.x;
  const int w = t >> 6, l = t & 63, g = l >> 4, c = l & 15;
  const int wr = w >> 1, wc = w & 1;
  const int bm = blockIdx.y, bn = blockIdx.x;

  f32x4 acc[4][4] = {};
  int nk = K >> 5, kk0 = 0;
  if (EPI == 4) { nk = nk / gridDim.z; kk0 = blockIdx.z * nk; }

  const int srow = t >> 2;
  const int sj = t & 3;
  const char* Abase = (const char*)A;
  const char* Bbase = (const char*)B;

  for (int kk = kk0; kk < kk0 + nk; ++kk) {
    const size_t kb = (size_t)kk * 64;
    uint4 a0 = *(const uint4*)(Abase + ((size_t)(bm * 128 + srow) * K) * 2 + kb + sj * 16);
    uint4 a1 = *(const uint4*)(Abase + ((size_t)(bm * 128 + srow + 64) * K) * 2 + kb + sj * 16);
    uint4 b0 = *(const uint4*)(Bbase + ((size_t)(bn * 128 + srow) * K) * 2 + kb + sj * 16);
    uint4 b1 = *(const uint4*)(Bbase + ((size_t)(bn * 128 + srow + 64) * K) * 2 + kb + sj * 16);
    __syncthreads();
    const int sw0 = (sj * 16) ^ (((srow >> 1) & 3) << 4);
    const int sw1 = (sj * 16) ^ ((((srow + 64) >> 1) & 3) << 4);
    *(uint4*)((char*)As + srow * 64 + sw0) = a0;
    *(uint4*)((char*)As + (srow + 64) * 64 + sw1) = a1;
    *(uint4*)((char*)Bs + srow * 64 + sw0) = b0;
    *(uint4*)((char*)Bs + (srow + 64) * 64 + sw1) = b1;
    __syncthreads();
    short8 af[4], bfr[4];
#pragma unroll
    for (int m = 0; m < 4; ++m) {
      int row = wr * 64 + m * 16 + c;
      af[m] = ldfrag((const char*)As + row * 64 + ((g * 16) ^ (((row >> 1) & 3) << 4)));
    }
#pragma unroll
    for (int n = 0; n < 4; ++n) {
      int row = wc * 64 + n * 16 + c;
      bfr[n] = ldfrag((const char*)Bs + row * 64 + ((g * 16) ^ (((row >> 1) & 3) << 4)));
    }
#pragma unroll
    for (int m = 0; m < 4; ++m)
#pragma unroll
      for (int n = 0; n < 4; ++n) acc[m][n] = MFMA16(af[m], bfr[n], acc[m][n]);
  }

  const int row0 = bm * 128 + wr * 64 + 4 * g;
  const int col0 = bn * 128 + wc * 64 + c;
#pragma unroll
  for (int m = 0; m < 4; ++m) {
#pragma unroll
    for (int n = 0; n < 4; ++n) {
      const int row = row0 + m * 16;
      const int col = col0 + n * 16;
      if (EPI == 0) {
#pragma unroll
        for (int rr = 0; rr < 4; ++rr)
          ((u16*)out)[(size_t)(row + rr) * N + col] = f2b(acc[m][n][rr]);
      } else if (EPI == 1) {
        ushort4 o = { f2b(acc[m][n][0]), f2b(acc[m][n][1]), f2b(acc[m][n][2]), f2b(acc[m][n][3]) };
        *(ushort4*)((u16*)out + (size_t)col * M + row) = o;
      } else if (EPI == 2) {
        float bc = bias[col];
#pragma unroll
        for (int rr = 0; rr < 4; ++rr) {
          size_t idx = (size_t)(row + rr) * N + col;
          ((float*)out)[idx] = acc[m][n][rr] + bc + resid[idx];
        }
      } else if (EPI == 3) {
        float bc = bias[col];
#pragma unroll
        for (int rr = 0; rr < 4; ++rr)
          ((u16*)out)[(size_t)(row + rr) * N + col] = f2b(gelu_exact(acc[m][n][rr] + bc));
      } else {
        float* po = (float*)out + (size_t)blockIdx.z * M * N;
#pragma unroll
        for (int rr = 0; rr < 4; ++rr)
          po[(size_t)(row + rr) * N + col] = acc[m][n][rr];
      }
    }
  }
}

// ---------------- reduce 4 split-K partials + bias + residual -> f32 ----------------
__global__ __launch_bounds__(256) void k_red4(const float* __restrict__ p,
                                              const float* __restrict__ bias,
                                              const float* __restrict__ resid,
                                              float* __restrict__ out) {
  int i = blockIdx.x * 256 + threadIdx.x;
  const float4* p4 = (const float4*)p;
  float4 a = p4[i], b = p4[i + 262144], c = p4[i + 524288], d = p4[i + 786432];
  float4 r = ((const float4*)resid)[i];
  float4 bb = ((const float4*)bias)[i & 63];
  float4 o;
  o.x = a.x + b.x + c.x + d.x + r.x + bb.x;
  o.y = a.y + b.y + c.y + d.y + r.y + bb.y;
  o.z = a.z + b.z + c.z + d.z + r.z + bb.z;
  o.w = a.w + b.w + c.w + d.w + r.w + bb.w;
  ((float4*)out)[i] = o;
}

// ---------------- Flash attention (kv-split-2): 8 heads, d_head=256, N=4096 ----------------
// 32x32x16 MFMA, swapped QK^T (A=K,B=Q), 4 waves x 32 q, KVBLK=32, dbuf 64KB LDS (2 blocks/CU),
// in-register P via cvt_pk_bf16 + permlane32_swap. Writes unnormalized bf16 partials + (m,l).
__global__ __launch_bounds__(256, 2) void k_attn(const u16* __restrict__ Q,
                                                 const u16* __restrict__ Km,
                                                 const u16* __restrict__ VT,
                                                 u16* __restrict__ part,
                                                 float* __restrict__ ml) {
  __shared__ __attribute__((aligned(16))) char smem[65536];
  const int t = threadIdx.x;
  const int w = t >> 6, l = t & 63;
  const int q31 = l & 31, hi = l >> 5;
  const int head = blockIdx.x, qb = blockIdx.y, sp = blockIdx.z;
  const int kvbase = sp * 2048;
  const float C2 = 0.0625f * 1.44269504f;  // 1/sqrt(256) * log2(e)

  short8 qf[16];
  {
    const char* qp = (const char*)Q + (size_t)(qb * 128 + w * 32 + q31) * 4096 + head * 512 + hi * 16;
#pragma unroll
    for (int ks = 0; ks < 16; ++ks) qf[ks] = ldfrag(qp + ks * 32);
  }

  f32x16 o[8] = {};
  float m = -1e30f, lsum = 0.0f;

  const char* KbaseH = (const char*)Km + head * 512;
  const char* VbaseH = (const char*)VT + (size_t)head * 256 * 8192;

  auto stage = [&](int c) {
    const int buf = c & 1;
    const int kv0 = kvbase + c * 32;
    char* kd = smem + buf * 16384;
    char* vd = smem + 32768 + buf * 16384;
#pragma unroll
    for (int ii = 0; ii < 4; ++ii) {
      const int row = w * 8 + ii * 2 + hi;  // kv row; slot q31, source inverse-swizzled
      llds16(KbaseH + (size_t)(kv0 + row) * 4096 + ((q31 ^ row) << 4), kd + (w * 4 + ii) * 1024);
    }
#pragma unroll
    for (int ii = 0; ii < 4; ++ii) {
      const int row = w * 64 + ii * 16 + (l >> 2);  // d row; slot l&3
      llds16(VbaseH + (size_t)row * 8192 + (size_t)kv0 * 2 + (((l & 3) ^ ((row >> 3) & 3)) << 4),
             vd + (w * 4 + ii) * 1024);
    }
  };

  stage(0);
  for (int c = 0; c < 64; ++c) {
    asm volatile("s_waitcnt vmcnt(0)" ::: "memory");
    __builtin_amdgcn_s_barrier();
    __builtin_amdgcn_sched_barrier(0);
    if (c < 63) stage(c + 1);

    const char* kd = smem + (c & 1) * 16384;
    const char* vd = smem + 32768 + (c & 1) * 16384;

    // S^T = K . Q^T : C[kv][q], one 32-kv tile
    f32x16 s = {};
    const char* ka = kd + q31 * 512;
    const int sswz = q31 << 4;
#pragma unroll
    for (int ks = 0; ks < 16; ++ks) {
      short8 a0 = ldfrag(ka + ((ks * 32 + hi * 16) ^ sswz));
      s = MFMA32(a0, qf[ks], s);
    }

    // online softmax (kv lane-local: 16 values here + 16 in lane^32)
    float pm = s[0];
#pragma unroll
    for (int i = 1; i < 16; ++i) pm = fmaxf(pm, s[i]);
    pm = fmaxf(pm, __shfl_xor(pm, 32));
    if (__any(pm > m + 64.0f)) {
      float mn = fmaxf(m, pm);
      float sc = EXP2((m - mn) * C2);
      m = mn;
      lsum *= sc;
#pragma unroll
      for (int i = 0; i < 16; ++i) {
        const int r = (i & 3) + 8 * (i >> 2) + 4 * hi;
        float sclr = __shfl(sc, r);
#pragma unroll
        for (int dt = 0; dt < 8; ++dt) o[dt][i] *= sclr;
      }
    }
    const float mc2 = m * C2;
    float p[16];
    float rs = 0.f;
#pragma unroll
    for (int i = 0; i < 16; ++i) { p[i] = EXP2(fmaf(s[i], C2, -mc2)); rs += p[i]; }
    rs += __shfl_xor(rs, 32);
    lsum += rs;

    // in-register P -> A-fragments (q = lane&31 already correct; redistribute kv via permlane)
    u32 pk[8];
#pragma unroll
    for (int j = 0; j < 8; ++j)
      asm("v_cvt_pk_bf16_f32 %0, %1, %2" : "=v"(pk[j]) : "v"(p[2 * j]), "v"(p[2 * j + 1]));
    asm("v_permlane32_swap_b32 %0, %1" : "+v"(pk[0]), "+v"(pk[2]));
    asm("v_permlane32_swap_b32 %0, %1" : "+v"(pk[1]), "+v"(pk[3]));
    asm("v_permlane32_swap_b32 %0, %1" : "+v"(pk[4]), "+v"(pk[6]));
    asm("v_permlane32_swap_b32 %0, %1" : "+v"(pk[5]), "+v"(pk[7]));
    uint4 f0 = { pk[0], pk[1], pk[2], pk[3] };
    uint4 f1 = { pk[4], pk[5], pk[6], pk[7] };
    short8 pa0 = __builtin_bit_cast(short8, f0);
    short8 pa1 = __builtin_bit_cast(short8, f1);

    // O += P . V : B=V[kv][32d] from LDS (conflict-free swizzle), A=P in regs
#pragma unroll
    for (int dt = 0; dt < 8; ++dt) {
      const int row = dt * 32 + q31;
      const char* vr = vd + row * 64;
      const int vs = ((row >> 3) & 3) << 4;
      short8 b0 = ldfrag(vr + ((hi * 16) ^ vs));
      short8 b1 = ldfrag(vr + ((32 + hi * 16) ^ vs));
      o[dt] = MFMA32(pa0, b0, o[dt]);
      o[dt] = MFMA32(pa1, b1, o[dt]);
    }
  }

  // epilogue: unnormalized bf16 partial + (m, l)
  u16* pb = part + (size_t)sp * 4096 * 2048;
#pragma unroll
  for (int i = 0; i < 16; ++i) {
    const int r = (i & 3) + 8 * (i >> 2) + 4 * hi;
    const size_t qg = (size_t)(qb * 128 + w * 32 + r);
#pragma unroll
    for (int dt = 0; dt < 8; ++dt)
      pb[qg * 2048 + head * 256 + dt * 32 + q31] = f2b(o[dt][i]);
  }
  if (hi == 0) {
    const int qg = qb * 128 + w * 32 + q31;
    ml[((sp * 2 + 0) * 8 + head) * 4096 + qg] = m;
    ml[((sp * 2 + 1) * 8 + head) * 4096 + qg] = lsum;
  }
}

// ---------------- merge 2 kv-split partials ----------------
__global__ __launch_bounds__(256) void k_merge(const u16* __restrict__ part,
                                               const float* __restrict__ ml,
                                               u16* __restrict__ outp) {
  const int row = blockIdx.x;       // 4096
  const int t = threadIdx.x;        // 8 cols each
  const int c0 = t * 8;
  const int head = t >> 5;
  const float C2 = 0.0625f * 1.44269504f;
  float m0 = ml[(0 + head) * 4096 + row];
  float l0 = ml[(8 + head) * 4096 + row];
  float m1 = ml[(16 + head) * 4096 + row];
  float l1 = ml[(24 + head) * 4096 + row];
  float M = fmaxf(m0, m1);
  float w0 = EXP2((m0 - M) * C2), w1 = EXP2((m1 - M) * C2);
  float inv = 1.0f / (l0 * w0 + l1 * w1);
  w0 *= inv;
  w1 *= inv;
  const size_t base = (size_t)row * 2048 + c0;
  uint4 a = *(const uint4*)(part + base);
  uint4 b = *(const uint4*)(part + (size_t)4096 * 2048 + base);
  const u16* ah = (const u16*)&a;
  const u16* bh = (const u16*)&b;
  ushort4 o0, o1;
  u16* oh0 = (u16*)&o0;
  u16* oh1 = (u16*)&o1;
#pragma unroll
  for (int j = 0; j < 4; ++j) {
    oh0[j] = f2b(b2f(ah[j]) * w0 + b2f(bh[j]) * w1);
    oh1[j] = f2b(b2f(ah[j + 4]) * w0 + b2f(bh[j + 4]) * w1);
  }
  *(ushort4*)(outp + base) = o0;
  *(ushort4*)(outp + base + 4) = o1;
}

// ---------------- launch ----------------
extern "C" void kernel_launch(void* const* d_in, const int* in_sizes, int n_in,
                              void* d_out, int out_size, void* d_ws, size_t ws_size,
                              hipStream_t stream) {
  const float* x   = (const float*)d_in[0];
  const float* Wq  = (const float*)d_in[1];
  const float* Wk  = (const float*)d_in[2];
  const float* Wv  = (const float*)d_in[3];
  const float* Wo  = (const float*)d_in[4];
  const float* bo  = (const float*)d_in[5];
  const float* g1  = (const float*)d_in[6];
  const float* be1 = (const float*)d_in[7];
  const float* g2  = (const float*)d_in[8];
  const float* be2 = (const float*)d_in[9];
  const float* W1  = (const float*)d_in[10];
  const float* b1  = (const float*)d_in[11];
  const float* W2  = (const float*)d_in[12];
  const float* b2  = (const float*)d_in[13];

  char* ws = (char*)d_ws;
  size_t off = 0;
  auto alloc = [&](size_t n) {
    char* p = ws + off;
    off = (off + n + 255) & ~(size_t)255;
    return p;
  };
  u16* hb    = (u16*)alloc(4096 * 256 * 2);
  u16* Wqb   = (u16*)alloc(2048 * 256 * 2);
  u16* Wkb   = (u16*)alloc(2048 * 256 * 2);
  u16* Wvb   = (u16*)alloc(2048 * 256 * 2);
  u16* Wob   = (u16*)alloc(256 * 2048 * 2);
  u16* W1b   = (u16*)alloc(1024 * 256 * 2);
  u16* W2b   = (u16*)alloc(256 * 1024 * 2);
  u16* Qb    = (u16*)alloc((size_t)4096 * 2048 * 2);
  u16* Kb    = (u16*)alloc((size_t)4096 * 2048 * 2);
  u16* VTb   = (u16*)alloc((size_t)2048 * 4096 * 2);
  u16* attnb = (u16*)alloc((size_t)2 * 4096 * 2048 * 2);  // 2 kv-split partials; final in slot 0
  float* mlb = (float*)alloc(32 * 4096 * 4);
  float* x2  = (float*)alloc(4096 * 256 * 4);
  u16* h2b   = (u16*)alloc(4096 * 256 * 2);
  u16* ffn1  = (u16*)alloc((size_t)4096 * 1024 * 2);
  float* pbuf = (float*)Qb;  // 16MB, dead after k_attn: 4x [4096][256] f32 split-K partials

  k_f2bm<<<dim3(512, 6), 256, 0, stream>>>(Wq, Wk, Wv, Wo, W1, W2, Wqb, Wkb, Wvb, Wob, W1b, W2b);

  k_ln<<<1024, 256, 0, stream>>>(x, g1, be1, hb);

  k_gemm<0><<<dim3(16, 32), 256, 0, stream>>>(hb, Wqb, Qb, nullptr, nullptr, 4096, 2048, 256);
  k_gemm<0><<<dim3(16, 32), 256, 0, stream>>>(hb, Wkb, Kb, nullptr, nullptr, 4096, 2048, 256);
  k_gemm<1><<<dim3(16, 32), 256, 0, stream>>>(hb, Wvb, VTb, nullptr, nullptr, 4096, 2048, 256);

  k_attn<<<dim3(8, 32, 2), 256, 0, stream>>>(Qb, Kb, VTb, attnb, mlb);
  k_merge<<<4096, 256, 0, stream>>>(attnb, mlb, attnb);

  k_gemm<4><<<dim3(2, 32, 4), 256, 0, stream>>>(attnb, Wob, pbuf, nullptr, nullptr, 4096, 256, 2048);
  k_red4<<<1024, 256, 0, stream>>>(pbuf, bo, x, x2);
  k_ln<<<1024, 256, 0, stream>>>(x2, g2, be2, h2b);
  k_gemm<3><<<dim3(8, 32), 256, 0, stream>>>(h2b, W1b, ffn1, b1, nullptr, 4096, 1024, 256);
  k_gemm<4><<<dim3(2, 32, 4), 256, 0, stream>>>(ffn1, W2b, pbuf, nullptr, nullptr, 4096, 256, 1024);
  k_red4<<<1024, 256, 0, stream>>>(pbuf, b2, x2, (float*)d_out);
}